// Round 1
// baseline (269.588 us; speedup 1.0000x reference)
//
#include <hip/hip_runtime.h>
#include <hip/hip_bf16.h>

// Problem constants
#define N      8192
#define D_IN   30
#define HID    32
#define D_OUT  30
#define FFD    128
#define ZC     34      // Z columns = D_IN + P_DIM + 1
#define TJ     64      // j-tile staged in LDS

// ---------------------------------------------------------------------------
// Kernel A: Q = F@Wq+bq, K, V, plus packed (p0,p1,p2,|p|^2) per row.
// Thread t -> (i = t/32, h = t%32). W reads coalesced across h; Z broadcast.
// ---------------------------------------------------------------------------
__global__ __launch_bounds__(256) void dv_qkv_kernel(
    const float* __restrict__ Z,
    const float* __restrict__ Wq, const float* __restrict__ bq,
    const float* __restrict__ Wk, const float* __restrict__ bk,
    const float* __restrict__ Wv, const float* __restrict__ bv,
    float* __restrict__ Q, float* __restrict__ K, float* __restrict__ V,
    float* __restrict__ Pn)
{
    int t = blockIdx.x * 256 + threadIdx.x;
    int i = t >> 5;
    int h = t & 31;
    const float* z = Z + (size_t)i * ZC;

    float q = bq[h], k = bk[h], v = bv[h];
#pragma unroll
    for (int d = 0; d < D_IN; ++d) {
        float zf = z[d];
        q = fmaf(zf, Wq[d * HID + h], q);
        k = fmaf(zf, Wk[d * HID + h], k);
        v = fmaf(zf, Wv[d * HID + h], v);
    }
    Q[(size_t)i * HID + h] = q;
    K[(size_t)i * HID + h] = k;
    V[(size_t)i * HID + h] = v;

    if (h == 0) {
        float p0 = z[D_IN], p1 = z[D_IN + 1], p2 = z[D_IN + 2];
        float4 pp;
        pp.x = p0; pp.y = p1; pp.z = p2;
        pp.w = p0 * p0 + p1 * p1 + p2 * p2;
        ((float4*)Pn)[i] = pp;
    }
}

// ---------------------------------------------------------------------------
// Kernel B: fused attention partial.
// Block = 256 threads; block (rb, jg): rows [rb*256, rb*256+256), each thread
// owns one row; j-chunk [jg*jlen, (jg+1)*jlen) walked in LDS tiles of TJ.
// Accumulates av[32] (= sum_j a_ij * V_j) and s (= sum_j a_ij) in registers.
// Writes partials to ws laid out [jg][c][i] (c = 0..31 av, 32 = s), coalesced.
// ---------------------------------------------------------------------------
__global__ __launch_bounds__(256) void dv_attn_kernel(
    const float* __restrict__ Q, const float* __restrict__ K,
    const float* __restrict__ V, const float* __restrict__ Pn,
    float* __restrict__ partial, int JG)
{
    __shared__ float4 sK4[TJ * 8];
    __shared__ float4 sV4[TJ * 8];
    __shared__ float4 sP4[TJ];

    const int tid = threadIdx.x;
    const int bi  = blockIdx.x;
    const int jg  = bi % JG;
    const int rb  = bi / JG;
    const int i   = rb * 256 + tid;
    const int jlen = N / JG;
    const int ntiles = jlen / TJ;

    // Own row's Q fragment and position
    const float4* Q4 = (const float4*)(Q + (size_t)i * HID);
    float4 qv[8];
#pragma unroll
    for (int q = 0; q < 8; ++q) qv[q] = Q4[q];
    float4 pi = ((const float4*)Pn)[i];

    float4 av[8];
#pragma unroll
    for (int q = 0; q < 8; ++q) { av[q].x = 0.f; av[q].y = 0.f; av[q].z = 0.f; av[q].w = 0.f; }
    float ssum = 0.f;

    const float4* K4 = (const float4*)K;
    const float4* V4 = (const float4*)V;
    const float4* P4 = (const float4*)Pn;

    for (int tile = 0; tile < ntiles; ++tile) {
        const int t0 = jg * jlen + tile * TJ;
        __syncthreads();
        // stage TJ rows of K, V (8 float4 each) and P (1 float4 each)
        for (int idx = tid; idx < TJ * 8 * 2 + TJ; idx += 256) {
            if (idx < TJ * 8)           sK4[idx]            = K4[(size_t)t0 * 8 + idx];
            else if (idx < TJ * 16)     sV4[idx - TJ * 8]   = V4[(size_t)t0 * 8 + (idx - TJ * 8)];
            else                        sP4[idx - TJ * 16]  = P4[t0 + (idx - TJ * 16)];
        }
        __syncthreads();

#pragma unroll 2
        for (int jj = 0; jj < TJ; ++jj) {
            // q . k
            float4 acc = {0.f, 0.f, 0.f, 0.f};
#pragma unroll
            for (int q = 0; q < 8; ++q) {
                float4 kk = sK4[jj * 8 + q];
                acc.x = fmaf(qv[q].x, kk.x, acc.x);
                acc.y = fmaf(qv[q].y, kk.y, acc.y);
                acc.z = fmaf(qv[q].z, kk.z, acc.z);
                acc.w = fmaf(qv[q].w, kk.w, acc.w);
            }
            float dot = (acc.x + acc.y) + (acc.z + acc.w);
            float sc  = dot * 0.17677669529663687f;   // 1/sqrt(32)

            float4 pp = sP4[jj];
            float pd = fmaf(pi.x, pp.x, fmaf(pi.y, pp.y, pi.z * pp.z));
            float d2 = fmaxf(pi.w + pp.w - 2.0f * pd, 0.0f);
            float decay = __expf(d2 * (-1.0f / 0.18f));     // exp(-d2/(2*sigma^2))
            // a = sigmoid(sc) * decay
            float a = decay * __builtin_amdgcn_rcpf(1.0f + __expf(-sc));

            ssum += a;
#pragma unroll
            for (int q = 0; q < 8; ++q) {
                float4 vv = sV4[jj * 8 + q];
                av[q].x = fmaf(a, vv.x, av[q].x);
                av[q].y = fmaf(a, vv.y, av[q].y);
                av[q].z = fmaf(a, vv.z, av[q].z);
                av[q].w = fmaf(a, vv.w, av[q].w);
            }
        }
    }

    // write partials: [jg][c][i], c in 0..32
    const float avf[8][4] = {
        {av[0].x, av[0].y, av[0].z, av[0].w}, {av[1].x, av[1].y, av[1].z, av[1].w},
        {av[2].x, av[2].y, av[2].z, av[2].w}, {av[3].x, av[3].y, av[3].z, av[3].w},
        {av[4].x, av[4].y, av[4].z, av[4].w}, {av[5].x, av[5].y, av[5].z, av[5].w},
        {av[6].x, av[6].y, av[6].z, av[6].w}, {av[7].x, av[7].y, av[7].z, av[7].w}};
#pragma unroll
    for (int q = 0; q < 8; ++q)
#pragma unroll
        for (int c = 0; c < 4; ++c)
            partial[((size_t)(jg * 33 + (q * 4 + c))) * N + i] = avf[q][c];
    partial[((size_t)(jg * 33 + 32)) * N + i] = ssum;
}

// ---------------------------------------------------------------------------
// Kernel C: reduce partials + epilogue.
// Block = 256 threads handles 64 rows. Phase 1: cooperative reduction of JG
// partials into LDS. Phase 2: each row handled by 4 threads (tid&63 = row,
// tid>>6 = FF-dim quarter). Phase 3: wave 0 reduces FFN partials, applies
// We, computes ke, writes the 34-float output row.
// ---------------------------------------------------------------------------
__global__ __launch_bounds__(256) void dv_epilogue_kernel(
    const float* __restrict__ partial, int JG,
    const float* __restrict__ Wo, const float* __restrict__ bo,
    const float* __restrict__ ln_g, const float* __restrict__ ln_b,
    const float* __restrict__ W1, const float* __restrict__ b1,
    const float* __restrict__ W2, const float* __restrict__ b2,
    const float* __restrict__ We, const float* __restrict__ be,
    float* __restrict__ out)
{
    __shared__ float red[33][64];     // reduced av[32] + s per row
    __shared__ float red2[D_OUT][256]; // FFN partial outputs

    const int tid  = threadIdx.x;
    const int row0 = blockIdx.x * 64;

    // Phase 1: reduce partials over jg
    for (int idx = tid; idx < 33 * 64; idx += 256) {
        int c  = idx >> 6;
        int il = idx & 63;
        float s = 0.f;
        for (int jg = 0; jg < JG; ++jg)
            s += partial[((size_t)(jg * 33 + c)) * N + row0 + il];
        red[c][il] = s;
    }
    __syncthreads();

    const int il = tid & 63;
    const int c4 = tid >> 6;
    const int i  = row0 + il;

    float inv = 1.0f / (red[32][il] + 1e-8f);

    // H = (A@V)@Wo + bo
    float H[D_OUT];
#pragma unroll
    for (int o = 0; o < D_OUT; ++o) H[o] = bo[o];
    for (int h = 0; h < HID; ++h) {
        float a = red[h][il] * inv;
#pragma unroll
        for (int o = 0; o < D_OUT; ++o) H[o] = fmaf(a, Wo[h * D_OUT + o], H[o]);
    }

    // LayerNorm
    float mu = 0.f;
#pragma unroll
    for (int o = 0; o < D_OUT; ++o) mu += H[o];
    mu *= (1.0f / D_OUT);
    float var = 0.f;
#pragma unroll
    for (int o = 0; o < D_OUT; ++o) { float d = H[o] - mu; var = fmaf(d, d, var); }
    var *= (1.0f / D_OUT);
    float rs = rsqrtf(var + 1e-5f);
    float Hn[D_OUT];
#pragma unroll
    for (int o = 0; o < D_OUT; ++o)
        Hn[o] = fmaf((H[o] - mu) * rs, ln_g[o], ln_b[o]);

    // FFN quarter: f in [c4*32, c4*32+32)
    float o2[D_OUT];
#pragma unroll
    for (int o = 0; o < D_OUT; ++o) o2[o] = 0.f;
    for (int f = c4 * 32; f < c4 * 32 + 32; ++f) {
        float acc = b1[f];
#pragma unroll
        for (int o = 0; o < D_OUT; ++o) acc = fmaf(Hn[o], W1[o * FFD + f], acc);
        float hf = acc * __builtin_amdgcn_rcpf(1.0f + __expf(-acc)); // silu
#pragma unroll
        for (int o = 0; o < D_OUT; ++o) o2[o] = fmaf(hf, W2[f * D_OUT + o], o2[o]);
    }
#pragma unroll
    for (int o = 0; o < D_OUT; ++o) red2[o][tid] = o2[o];
    __syncthreads();

    // Phase 3: wave 0 finishes rows
    if (tid < 64) {
        float H2[D_OUT];
#pragma unroll
        for (int o = 0; o < D_OUT; ++o)
            H2[o] = red2[o][tid] + red2[o][tid + 64] + red2[o][tid + 128] +
                    red2[o][tid + 192] + b2[o];
        float* op = out + (size_t)i * ZC;
        float ke = 0.f;
#pragma unroll
        for (int o = 0; o < D_OUT; ++o) {
            float acc = be[o];
#pragma unroll
            for (int d = 0; d < D_OUT; ++d) acc = fmaf(H2[d], We[d * D_OUT + o], acc);
            op[o] = acc;
            ke = fmaf(acc, acc, ke);
        }
        op[30] = 0.f; op[31] = 0.f; op[32] = 0.f;
        op[33] = ke * (0.5f / 30.0f);
    }
}

// ---------------------------------------------------------------------------
extern "C" void kernel_launch(void* const* d_in, const int* in_sizes, int n_in,
                              void* d_out, int out_size, void* d_ws, size_t ws_size,
                              hipStream_t stream)
{
    const float* Z  = (const float*)d_in[1];
    const float* Wq = (const float*)d_in[2];
    const float* bq = (const float*)d_in[3];
    const float* Wk = (const float*)d_in[4];
    const float* bk = (const float*)d_in[5];
    const float* Wv = (const float*)d_in[6];
    const float* bv = (const float*)d_in[7];
    const float* Wo = (const float*)d_in[8];
    const float* bo = (const float*)d_in[9];
    const float* lg = (const float*)d_in[10];
    const float* lb = (const float*)d_in[11];
    const float* W1 = (const float*)d_in[12];
    const float* b1 = (const float*)d_in[13];
    const float* W2 = (const float*)d_in[14];
    const float* b2 = (const float*)d_in[15];
    const float* We = (const float*)d_in[16];
    const float* be = (const float*)d_in[17];
    float* out = (float*)d_out;

    float* ws = (float*)d_ws;
    float* Q  = ws;
    float* K  = Q + (size_t)N * HID;
    float* V  = K + (size_t)N * HID;
    float* Pn = V + (size_t)N * HID;
    float* partial = Pn + (size_t)N * 4;

    size_t base_bytes = ((size_t)3 * N * HID + (size_t)N * 4) * 4;
    int JG = 16;
    while (JG > 1 && base_bytes + (size_t)JG * 33 * N * 4 > ws_size) JG >>= 1;

    hipLaunchKernelGGL(dv_qkv_kernel, dim3((N * HID) / 256), dim3(256), 0, stream,
                       Z, Wq, bq, Wk, bk, Wv, bv, Q, K, V, Pn);
    hipLaunchKernelGGL(dv_attn_kernel, dim3(32 * JG), dim3(256), 0, stream,
                       Q, K, V, Pn, partial, JG);
    hipLaunchKernelGGL(dv_epilogue_kernel, dim3(N / 64), dim3(256), 0, stream,
                       partial, JG, Wo, bo, lg, lb, W1, b1, W2, b2, We, be, out);
}

// Round 3
// 74.169 us; speedup vs baseline: 3.6348x; 3.6348x over previous
//
#include <hip/hip_runtime.h>
#include <hip/hip_bf16.h>

#define N      8192
#define D_IN   30
#define HID    32
#define D_OUT  30
#define FFD    128
#define ZC     34

typedef __attribute__((ext_vector_type(8))) short short8;
typedef __attribute__((ext_vector_type(16))) float f32x16;

static __device__ __forceinline__ ushort f2bf(float x) {
    uint32_t u = __float_as_uint(x);
    uint32_t r = (u + 0x7fffu + ((u >> 16) & 1u)) >> 16;   // RTNE
    return (ushort)r;
}

// ---------------------------------------------------------------------------
// Kernel A: QKV projections -> bf16, V transposed to Vt[32][N], and
// P' = (sqrt(2c)*p, -c*|p|^2) with c = log2e/(2*sigma^2). Q pre-scaled by
// log2e/sqrt(HID) so the QK MFMA output is directly the exp2 exponent.
// ---------------------------------------------------------------------------
__global__ __launch_bounds__(256) void dv_qkv_kernel(
    const float* __restrict__ Z,
    const float* __restrict__ Wq, const float* __restrict__ bq,
    const float* __restrict__ Wk, const float* __restrict__ bk,
    const float* __restrict__ Wv, const float* __restrict__ bv,
    ushort* __restrict__ Qb, ushort* __restrict__ Kb,
    ushort* __restrict__ Vt, float4* __restrict__ Pg)
{
    __shared__ ushort sv[8][33];
    const int t = blockIdx.x * 256 + threadIdx.x;
    const int i = t >> 5;
    const int h = t & 31;
    const float* z = Z + (size_t)i * ZC;

    float q = bq[h], k = bk[h], v = bv[h];
#pragma unroll
    for (int d = 0; d < D_IN; ++d) {
        float zf = z[d];
        q = fmaf(zf, Wq[d * HID + h], q);
        k = fmaf(zf, Wk[d * HID + h], k);
        v = fmaf(zf, Wv[d * HID + h], v);
    }
    const float QS = 0.17677669529663687f * 1.4426950408889634f; // log2e/sqrt(32)
    Qb[(size_t)i * HID + h] = f2bf(q * QS);
    Kb[(size_t)i * HID + h] = f2bf(k);
    sv[threadIdx.x >> 5][h] = f2bf(v);

    if (h == 0) {
        float p0 = z[D_IN], p1 = z[D_IN + 1], p2 = z[D_IN + 2];
        const float C2 = 1.4426950408889634f / 0.18f;   // log2e/(2*sigma^2)
        const float SC = sqrtf(2.0f * C2);
        float4 pp;
        pp.x = p0 * SC; pp.y = p1 * SC; pp.z = p2 * SC;
        pp.w = -C2 * (p0 * p0 + p1 * p1 + p2 * p2);
        Pg[i] = pp;
    }
    __syncthreads();
    const int ho = threadIdx.x >> 3, io = threadIdx.x & 7;
    const int i0 = blockIdx.x * 8;
    Vt[(size_t)ho * N + i0 + io] = sv[io][ho];
}

// ---------------------------------------------------------------------------
// Kernel B: fused MFMA attention.
// Block = 256 thr = 4 waves; wave owns 32 i-rows. Grid = 64 row-blocks x 8 jg.
// Per 32-j tile: S^T = K @ Q^T (2 MFMA, A=K rows, B=Q rows, contiguous-8
// sourcing on both => k-mapping-agnostic). C/D layout (HW-verified):
// col=lane&31 (=i), row=(r&3)+8*(r>>2)+4*(lane>>5) (=j).
// Gate a = rcp(2^D + 2^(D-S')) in fp32. a packed to bf16 pairs IN PLACE
// (no cross-lane movement): lane (l31,h2) holds a[i=l31][j=4h2+(e&3)+8(e>>2)]
// (+16 for 2nd MFMA). PV feeds V through the SAME j-permutation via two 8B
// LDS reads per B-fragment => unknown k-mapping cancels.
// Outputs partial[jg][i][0..31]=A@V (unnormalized), [32]=rowsum.
// ---------------------------------------------------------------------------
__global__ __launch_bounds__(256, 2) void dv_attn_kernel(
    const ushort* __restrict__ Qb, const ushort* __restrict__ Kb,
    const ushort* __restrict__ Vt, const float4* __restrict__ Pg,
    float* __restrict__ partial)
{
    __shared__ ushort lK[128 * 32];   // K tile, 16B-chunk rot swizzle c'=(c+(j>>1))&3
    __shared__ ushort lV[32 * 128];   // V^T tile, 8B-chunk XOR swizzle c'=c^h
    __shared__ float4 lP[128];

    const int tid  = threadIdx.x;
    const int lane = tid & 63;
    const int wv   = tid >> 6;
    const int h2   = lane >> 5;
    const int l31  = lane & 31;
    const int rb   = blockIdx.x & 63;
    const int jg   = blockIdx.x >> 6;
    const int i0w  = rb * 128 + wv * 32;

    const ushort* qp = Qb + (size_t)(i0w + l31) * HID + h2 * 8;
    const short8 qf0 = *(const short8*)qp;
    const short8 qf1 = *(const short8*)(qp + 16);
    const float4 psi = Pg[i0w + l31];

    f32x16 zacc, oacc;
#pragma unroll
    for (int r = 0; r < 16; ++r) { zacc[r] = 0.f; oacc[r] = 0.f; }
    float ssum = 0.f;

    const int cA0 = (h2 + (l31 >> 1)) & 3;
    const int cA1 = (cA0 + 2) & 3;

    for (int ch = 0; ch < 8; ++ch) {
        const int j0 = (jg << 10) + (ch << 7);
        __syncthreads();
        {
            int idx = tid;
#pragma unroll
            for (int rep = 0; rep < 2; ++rep, idx += 256) {
                int jr = idx >> 2, c = idx & 3;
                int c2 = (c + (jr >> 1)) & 3;
                *(uint4*)&lK[jr * 32 + c2 * 8] =
                    *(const uint4*)&Kb[(size_t)(j0 + jr) * HID + c * 8];
            }
            idx = tid;
#pragma unroll
            for (int rep = 0; rep < 4; ++rep, idx += 256) {
                int hh = idx >> 5, cc = idx & 31;
                int cs = cc ^ hh;
                *(uint2*)&lV[hh * 128 + cs * 4] =
                    *(const uint2*)&Vt[(size_t)hh * N + j0 + cc * 4];
            }
            if (tid < 128) lP[tid] = Pg[j0 + tid];
        }
        __syncthreads();

#pragma unroll
        for (int t32 = 0; t32 < 4; ++t32) {
            const ushort* krow = &lK[(t32 * 32 + l31) * 32];
            short8 kf0 = *(const short8*)&krow[cA0 * 8];
            short8 kf1 = *(const short8*)&krow[cA1 * 8];
            f32x16 s = __builtin_amdgcn_mfma_f32_32x32x16_bf16(kf0, qf0, zacc, 0, 0, 0);
            s = __builtin_amdgcn_mfma_f32_32x32x16_bf16(kf1, qf1, s, 0, 0, 0);

            const float* lPf = (const float*)lP + (t32 * 32 + h2 * 4) * 4;
            uint32_t pk[8];
#pragma unroll
            for (int p = 0; p < 8; ++p) {
                const int jb = ((2 * p) & 3) + 8 * (p >> 1);   // + h2*4 via lPf row
                float4 pj0 = *(const float4*)(lPf + jb * 4);
                float4 pj1 = *(const float4*)(lPf + jb * 4 + 4);
                float t0 = fmaf(psi.x, pj0.x, pj0.w);
                t0 = fmaf(psi.y, pj0.y, t0);
                t0 = fmaf(psi.z, pj0.z, t0);
                t0 = fminf(t0 + psi.w, 0.f);          // -D0  (<= 0)
                float t1 = fmaf(psi.x, pj1.x, pj1.w);
                t1 = fmaf(psi.y, pj1.y, t1);
                t1 = fmaf(psi.z, pj1.z, t1);
                t1 = fminf(t1 + psi.w, 0.f);          // -D1
                float e0a = __builtin_amdgcn_exp2f(-t0);            // 2^D
                float e0b = __builtin_amdgcn_exp2f(-(t0 + s[2*p])); // 2^(D-S')
                float a0  = __builtin_amdgcn_rcpf(e0a + e0b);
                float e1a = __builtin_amdgcn_exp2f(-t1);
                float e1b = __builtin_amdgcn_exp2f(-(t1 + s[2*p+1]));
                float a1  = __builtin_amdgcn_rcpf(e1a + e1b);
                ssum += a0;
                ssum += a1;
                pk[p] = (uint32_t)f2bf(a0) | ((uint32_t)f2bf(a1) << 16);
            }
            union BV { uint32_t u[4]; short8 v; };
            BV fa, fb;
            fa.u[0] = pk[0]; fa.u[1] = pk[1]; fa.u[2] = pk[2]; fa.u[3] = pk[3];
            fb.u[0] = pk[4]; fb.u[1] = pk[5]; fb.u[2] = pk[6]; fb.u[3] = pk[7];

            // B-fragments: V rows through the SAME j-permutation as fa/fb.
            // 4-elem chunk index (logical) cb + {0,2} for MFMA1, cb + {4,6} for MFMA2.
            const ushort* vrow = &lV[l31 * 128];
            const int cb = t32 * 8 + h2;
            BV b0, b1;
            *(uint2*)&b0.u[0] = *(const uint2*)&vrow[((cb    ) ^ l31) * 4];
            *(uint2*)&b0.u[2] = *(const uint2*)&vrow[((cb + 2) ^ l31) * 4];
            *(uint2*)&b1.u[0] = *(const uint2*)&vrow[((cb + 4) ^ l31) * 4];
            *(uint2*)&b1.u[2] = *(const uint2*)&vrow[((cb + 6) ^ l31) * 4];

            oacc = __builtin_amdgcn_mfma_f32_32x32x16_bf16(fa.v, b0.v, oacc, 0, 0, 0);
            oacc = __builtin_amdgcn_mfma_f32_32x32x16_bf16(fb.v, b1.v, oacc, 0, 0, 0);
        }
    }

    float sst = ssum + __shfl_xor(ssum, 32, 64);
    const size_t pbase = (size_t)jg * N * 33;
    if (lane < 32)
        partial[pbase + (size_t)(i0w + lane) * 33 + 32] = sst;
#pragma unroll
    for (int r = 0; r < 16; ++r) {
        int ir = (r & 3) + 8 * (r >> 2) + 4 * h2 + i0w;
        partial[pbase + (size_t)ir * 33 + l31] = oacc[r];
    }
}

// ---------------------------------------------------------------------------
// Kernel C: reduce 8 jg partials + full epilogue. 256 blocks x 256 thr,
// 32 rows/block, 8 threads per row (grp = tid>>5).
// ---------------------------------------------------------------------------
__global__ __launch_bounds__(256) void dv_epilogue_kernel(
    const float* __restrict__ partial,
    const float* __restrict__ Wo, const float* __restrict__ bo,
    const float* __restrict__ ln_g, const float* __restrict__ ln_b,
    const float* __restrict__ W1, const float* __restrict__ b1,
    const float* __restrict__ W2, const float* __restrict__ b2,
    const float* __restrict__ We, const float* __restrict__ be,
    float* __restrict__ out)
{
    __shared__ float red[33][32];
    __shared__ float Hl[D_OUT][32];
    __shared__ float Hn[D_OUT][32];
    __shared__ float red2[D_OUT][256];
    __shared__ float mvl[2][32];
    __shared__ float ker[8][32];

    const int tid  = threadIdx.x;
    const int row0 = blockIdx.x * 32;

    for (int idx = tid; idx < 33 * 32; idx += 256) {
        int il = idx / 33, c = idx - il * 33;
        float s = 0.f;
#pragma unroll
        for (int jg = 0; jg < 8; ++jg)
            s += partial[((size_t)jg * N + row0 + il) * 33 + c];
        red[c][il] = s;
    }
    __syncthreads();

    const int il = tid & 31, grp = tid >> 5;
    const int o0 = grp * 4, o1 = (o0 + 4 < D_OUT) ? o0 + 4 : D_OUT;
    {
        float inv = __builtin_amdgcn_rcpf(red[32][il] + 1e-8f);
        for (int o = o0; o < o1; ++o) {
            float acc = 0.f;
#pragma unroll
            for (int h = 0; h < HID; ++h)
                acc = fmaf(red[h][il], Wo[h * D_OUT + o], acc);
            Hl[o][il] = fmaf(inv, acc, bo[o]);
        }
    }
    __syncthreads();
    if (tid < 32) {
        float mu = 0.f;
#pragma unroll
        for (int o = 0; o < D_OUT; ++o) mu += Hl[o][tid];
        mu *= (1.0f / D_OUT);
        float var = 0.f;
#pragma unroll
        for (int o = 0; o < D_OUT; ++o) { float d = Hl[o][tid] - mu; var = fmaf(d, d, var); }
        var *= (1.0f / D_OUT);
        mvl[0][tid] = mu;
        mvl[1][tid] = rsqrtf(var + 1e-5f);
    }
    __syncthreads();
    {
        float mu = mvl[0][il], rs = mvl[1][il];
        for (int o = o0; o < o1; ++o)
            Hn[o][il] = fmaf((Hl[o][il] - mu) * rs, ln_g[o], ln_b[o]);
    }
    __syncthreads();
    {
        float o2[D_OUT];
#pragma unroll
        for (int o = 0; o < D_OUT; ++o) o2[o] = 0.f;
        const int f0 = grp * 16;
        for (int f = f0; f < f0 + 16; ++f) {
            float acc = b1[f];
#pragma unroll
            for (int o = 0; o < D_OUT; ++o)
                acc = fmaf(Hn[o][il], W1[o * FFD + f], acc);
            float u = __builtin_amdgcn_exp2f(acc * -1.4426950408889634f);
            float hf = acc * __builtin_amdgcn_rcpf(1.0f + u);   // silu
#pragma unroll
            for (int o = 0; o < D_OUT; ++o)
                o2[o] = fmaf(hf, W2[f * D_OUT + o], o2[o]);
        }
#pragma unroll
        for (int o = 0; o < D_OUT; ++o) red2[o][tid] = o2[o];
    }
    __syncthreads();
    {
        float H2[D_OUT];
#pragma unroll
        for (int d = 0; d < D_OUT; ++d) {
            float s = b2[d];
#pragma unroll
            for (int g = 0; g < 8; ++g) s += red2[d][il + 32 * g];
            H2[d] = s;
        }
        float kep = 0.f;
        float* op = out + (size_t)(row0 + il) * ZC;
        for (int o = o0; o < o1; ++o) {
            float acc = be[o];
#pragma unroll
            for (int d = 0; d < D_OUT; ++d)
                acc = fmaf(H2[d], We[d * D_OUT + o], acc);
            op[o] = acc;
            kep = fmaf(acc, acc, kep);
        }
        ker[grp][il] = kep;
    }
    __syncthreads();
    if (tid < 32) {
        float ke = 0.f;
#pragma unroll
        for (int g = 0; g < 8; ++g) ke += ker[g][tid];
        float* op = out + (size_t)(row0 + tid) * ZC;
        op[30] = 0.f; op[31] = 0.f; op[32] = 0.f;
        op[33] = ke * (0.5f / D_OUT);
    }
}

// ---------------------------------------------------------------------------
extern "C" void kernel_launch(void* const* d_in, const int* in_sizes, int n_in,
                              void* d_out, int out_size, void* d_ws, size_t ws_size,
                              hipStream_t stream)
{
    const float* Z  = (const float*)d_in[1];
    const float* Wq = (const float*)d_in[2];
    const float* bq = (const float*)d_in[3];
    const float* Wk = (const float*)d_in[4];
    const float* bk = (const float*)d_in[5];
    const float* Wv = (const float*)d_in[6];
    const float* bv = (const float*)d_in[7];
    const float* Wo = (const float*)d_in[8];
    const float* bo = (const float*)d_in[9];
    const float* lg = (const float*)d_in[10];
    const float* lb = (const float*)d_in[11];
    const float* W1 = (const float*)d_in[12];
    const float* b1 = (const float*)d_in[13];
    const float* W2 = (const float*)d_in[14];
    const float* b2 = (const float*)d_in[15];
    const float* We = (const float*)d_in[16];
    const float* be = (const float*)d_in[17];
    float* out = (float*)d_out;

    ushort* Qb = (ushort*)d_ws;                 // N*32 bf16
    ushort* Kb = Qb + (size_t)N * HID;          // N*32 bf16
    ushort* Vt = Kb + (size_t)N * HID;          // [32][N] bf16
    float4* Pg = (float4*)(Vt + (size_t)N * HID);
    float* partial = (float*)(Pg + N);          // [8][N][33] f32

    hipLaunchKernelGGL(dv_qkv_kernel, dim3((N * HID) / 256), dim3(256), 0, stream,
                       Z, Wq, bq, Wk, bk, Wv, bv, Qb, Kb, Vt, Pg);
    hipLaunchKernelGGL(dv_attn_kernel, dim3(512), dim3(256), 0, stream,
                       Qb, Kb, Vt, Pg, partial);
    hipLaunchKernelGGL(dv_epilogue_kernel, dim3(N / 32), dim3(256), 0, stream,
                       partial, Wo, bo, lg, lb, W1, b1, W2, b2, We, be, out);
}